// Round 1
// baseline (2770.030 us; speedup 1.0000x reference)
//
#include <hip/hip_runtime.h>
#include <math.h>

// ---------------------------------------------------------------------------
// VQ-VAE forward (eval): encoder convs -> VQ -> decoder convs (+transposed)
// All fp32, direct convolutions. Correctness-first round.
// ---------------------------------------------------------------------------

// conv1: x(32,2,400,600) w(64,2,10,11) s(8,9) p(1,1) -> y(32,64,50,66), +b, relu
__global__ __launch_bounds__(256) void conv1_k(const float* __restrict__ x,
                                               const float* __restrict__ w,
                                               const float* __restrict__ b,
                                               float* __restrict__ y)
{
    __shared__ float xs[2 * 10 * 596]; // 47.68 KB
    const int blk = blockIdx.x;            // 32*50 = 1600
    const int n = blk / 50, oh = blk % 50;
    const int tid = threadIdx.x;
    const int ih0 = oh * 8 - 1;
    for (int i = tid; i < 2 * 10 * 596; i += 256) {
        int c = i / 5960, rem = i % 5960;
        int r = rem / 596, j = rem % 596;
        int ih = ih0 + r, iw = j - 1;
        float v = 0.f;
        if (ih >= 0 && ih < 400 && iw >= 0 && iw < 600)
            v = x[((n * 2 + c) * 400 + ih) * 600 + iw];
        xs[i] = v;
    }
    __syncthreads();
    for (int i = tid; i < 32 * 66; i += 256) {
        int oc = i / 66, ow = i % 66;
        int col = ow * 9;
        float a0 = 0.f, a1 = 0.f;
        for (int c = 0; c < 2; ++c) {
            const float* wp0 = w + ((oc)        * 2 + c) * 110;
            const float* wp1 = w + ((oc + 32)   * 2 + c) * 110;
            const float* xp  = xs + c * 5960 + col;
            for (int kh = 0; kh < 10; ++kh) {
                #pragma unroll
                for (int kw = 0; kw < 11; ++kw) {
                    float xv = xp[kh * 596 + kw];
                    a0 += xv * wp0[kh * 11 + kw];
                    a1 += xv * wp1[kh * 11 + kw];
                }
            }
        }
        y[((n * 64 + oc)      * 50 + oh) * 66 + ow] = fmaxf(a0 + b[oc], 0.f);
        y[((n * 64 + oc + 32) * 50 + oh) * 66 + ow] = fmaxf(a1 + b[oc + 32], 0.f);
    }
}

// conv2: h1(32,64,50,66) w(128,64,12,12) s10 p1 -> y(32,128,5,6), +b, relu
__global__ __launch_bounds__(192) void conv2_k(const float* __restrict__ x,
                                               const float* __restrict__ w,
                                               const float* __restrict__ b,
                                               float* __restrict__ y)
{
    __shared__ float xs[16 * 12 * 63]; // 48.4 KB
    const int blk = blockIdx.x;        // 32*5 = 160
    const int n = blk / 5, oh = blk % 5;
    const int tid = threadIdx.x;       // 192 = 32 ocg * 6 ow
    const int ow = tid % 6, ocg = tid / 6;
    const int ih0 = oh * 10 - 1;
    float acc[4] = {0.f, 0.f, 0.f, 0.f};
    for (int cc = 0; cc < 4; ++cc) {
        __syncthreads();
        for (int i = tid; i < 16 * 12 * 63; i += 192) {
            int c = i / 756, rem = i % 756;
            int r = rem / 63, j = rem % 63;
            int ih = ih0 + r, iw = j - 1;
            float v = 0.f;
            if (ih >= 0 && ih < 50 && iw >= 0 && iw < 66)
                v = x[((n * 64 + cc * 16 + c) * 50 + ih) * 66 + iw];
            xs[i] = v;
        }
        __syncthreads();
        for (int c = 0; c < 16; ++c) {
            for (int kh = 0; kh < 12; ++kh) {
                const float* xp = xs + (c * 12 + kh) * 63 + ow * 10;
                #pragma unroll
                for (int kw = 0; kw < 12; ++kw) {
                    float xv = xp[kw];
                    #pragma unroll
                    for (int q = 0; q < 4; ++q) {
                        int oc = ocg + q * 32;
                        acc[q] += xv * w[((oc * 64 + cc * 16 + c) * 12 + kh) * 12 + kw];
                    }
                }
            }
        }
    }
    #pragma unroll
    for (int q = 0; q < 4; ++q) {
        int oc = ocg + q * 32;
        y[((n * 128 + oc) * 5 + oh) * 6 + ow] = fmaxf(acc[q] + b[oc], 0.f);
    }
}

// generic 3x3 conv on 5x6 spatial, pad 1, optional bias, optional relu on input
__global__ void conv3x3_k(const float* __restrict__ x, const float* __restrict__ w,
                          const float* __restrict__ b, float* __restrict__ y,
                          int Cin, int Cout, int relu_in)
{
    int idx = blockIdx.x * 256 + threadIdx.x;
    int total = 32 * Cout * 30;
    if (idx >= total) return;
    int ow = idx % 6, t = idx / 6;
    int oh = t % 5; t /= 5;
    int oc = t % Cout;
    int n = t / Cout;
    float acc = b ? b[oc] : 0.f;
    for (int kh = 0; kh < 3; ++kh) {
        int ih = oh - 1 + kh;
        if (ih < 0 || ih >= 5) continue;
        for (int kw = 0; kw < 3; ++kw) {
            int iw = ow - 1 + kw;
            if (iw < 0 || iw >= 6) continue;
            const float* xp = x + (n * Cin * 5 + ih) * 6 + iw;
            const float* wp = w + (oc * Cin * 3 + kh) * 3 + kw;
            #pragma unroll 4
            for (int c = 0; c < Cin; ++c) {
                float xv = xp[c * 30];
                if (relu_in) xv = fmaxf(xv, 0.f);
                acc += xv * wp[c * 9];
            }
        }
    }
    y[idx] = acc;
}

// residual 1x1: x(32,128,5,6) += sum_c w[o][c] * relu(t(32,64,5,6))
__global__ void res2_k(float* __restrict__ x, const float* __restrict__ t,
                       const float* __restrict__ w)
{
    int idx = blockIdx.x * 256 + threadIdx.x;
    if (idx >= 32 * 128 * 30) return;
    int ow = idx % 6;
    int oh = (idx / 6) % 5;
    int oc = (idx / 30) % 128;
    int n = idx / 3840;
    const float* tp = t + (n * 64 * 5 + oh) * 6 + ow;
    const float* wp = w + oc * 64;
    float acc = 0.f;
    #pragma unroll 4
    for (int c = 0; c < 64; ++c) acc += fmaxf(tp[c * 30], 0.f) * wp[c];
    x[idx] += acc;
}

// pre: z = conv1x1(relu(h)) 128->64 +b
__global__ void conv1x1_k(const float* __restrict__ x, const float* __restrict__ w,
                          const float* __restrict__ b, float* __restrict__ y)
{
    int idx = blockIdx.x * 256 + threadIdx.x;
    if (idx >= 32 * 64 * 30) return;
    int ow = idx % 6;
    int oh = (idx / 6) % 5;
    int oc = (idx / 30) % 64;
    int n = idx / 1920;
    const float* xp = x + (n * 128 * 5 + oh) * 6 + ow;
    const float* wp = w + oc * 128;
    float acc = b[oc];
    #pragma unroll 4
    for (int c = 0; c < 128; ++c) acc += fmaxf(xp[c * 30], 0.f) * wp[c];
    y[idx] = acc;
}

// VQ: per row (n,h,w): argmin_k ||z - e_k||^2; scatter q to NCHW; counts; loss partial
__global__ __launch_bounds__(64) void vq_k(const float* __restrict__ z,
                                           const float* __restrict__ emb,
                                           float* __restrict__ qn,
                                           float* __restrict__ counts,
                                           float* __restrict__ loss_sum)
{
    const int r = blockIdx.x;          // 0..959
    const int lane = threadIdx.x;      // 0..63
    const int n = r / 30, hw = r % 30;
    __shared__ float zs[64];
    zs[lane] = z[(n * 64 + lane) * 30 + hw];
    __syncthreads();
    float best = 1e30f;
    int bestk = 0;
    for (int j = 0; j < 8; ++j) {
        int k = lane + j * 64;
        const float* ep = emb + k * 64;
        float dist = 0.f;
        #pragma unroll 8
        for (int d = 0; d < 64; ++d) {
            float df = ep[d] - zs[d];
            dist += df * df;
        }
        if (dist < best) { best = dist; bestk = k; }
    }
    for (int off = 32; off > 0; off >>= 1) {
        float ob = __shfl_down(best, off);
        int ok = __shfl_down(bestk, off);
        if (ob < best || (ob == best && ok < bestk)) { best = ob; bestk = ok; }
    }
    bestk = __shfl(bestk, 0);
    float ev = emb[bestk * 64 + lane];
    qn[(n * 64 + lane) * 30 + hw] = ev;
    float df = ev - zs[lane];
    df *= df;
    for (int off = 32; off > 0; off >>= 1) df += __shfl_down(df, off);
    if (lane == 0) {
        atomicAdd(loss_sum, df);
        atomicAdd(&counts[bestk], 1.0f);
    }
}

// convT1: x(32,128,5,6) wt(128,64,12,12) s10 p1 -> y(32,64,50,60), +b, relu(in+out)
__global__ void convt1_k(const float* __restrict__ x, const float* __restrict__ w,
                         const float* __restrict__ b, float* __restrict__ y)
{
    int idx = blockIdx.x * 256 + threadIdx.x;
    if (idx >= 32 * 64 * 50 * 60) return;
    int ow = idx % 60, t = idx / 60;
    int oh = t % 50; t /= 50;
    int oc = t % 64;
    int n = t / 64;
    int khv[2], ihv[2], nh = 0;
    int rh = (oh + 1) % 10;
    { int ih = (oh + 1 - rh) / 10; if (ih < 5) { khv[nh] = rh; ihv[nh] = ih; nh++; } }
    if (rh + 10 < 12) { int ih = (oh + 1 - rh) / 10 - 1; if (ih >= 0) { khv[nh] = rh + 10; ihv[nh] = ih; nh++; } }
    int kwv[2], iwv[2], nw = 0;
    int rw = (ow + 1) % 10;
    { int iw = (ow + 1 - rw) / 10; if (iw < 6) { kwv[nw] = rw; iwv[nw] = iw; nw++; } }
    if (rw + 10 < 12) { int iw = (ow + 1 - rw) / 10 - 1; if (iw >= 0) { kwv[nw] = rw + 10; iwv[nw] = iw; nw++; } }
    float acc = b[oc];
    for (int a = 0; a < nh; ++a) {
        for (int bb = 0; bb < nw; ++bb) {
            const float* xp = x + (n * 128 * 5 + ihv[a]) * 6 + iwv[bb];
            const float* wp = w + (oc * 12 + khv[a]) * 12 + kwv[bb];
            #pragma unroll 4
            for (int c = 0; c < 128; ++c)
                acc += fmaxf(xp[c * 30], 0.f) * wp[c * 9216];
        }
    }
    y[idx] = fmaxf(acc, 0.f);
}

// convT2: x(32,64,50,60) wt(64,2,10,11) s(8,9) p1 -> y(32,2,400,540), +b
__global__ void convt2_k(const float* __restrict__ x, const float* __restrict__ w,
                         const float* __restrict__ b, float* __restrict__ y)
{
    int idx = blockIdx.x * 256 + threadIdx.x;
    if (idx >= 32 * 2 * 400 * 540) return;
    int ow = idx % 540, t = idx / 540;
    int oh = t % 400; t /= 400;
    int oc = t % 2;
    int n = t / 2;
    int khv[2], ihv[2], nh = 0;
    int rh = (oh + 1) % 8;
    { int ih = (oh + 1 - rh) / 8; if (ih < 50) { khv[nh] = rh; ihv[nh] = ih; nh++; } }
    if (rh + 8 < 10) { int ih = (oh + 1 - rh) / 8 - 1; if (ih >= 0) { khv[nh] = rh + 8; ihv[nh] = ih; nh++; } }
    int kwv[2], iwv[2], nw = 0;
    int rw = (ow + 1) % 9;
    { int iw = (ow + 1 - rw) / 9; if (iw < 60) { kwv[nw] = rw; iwv[nw] = iw; nw++; } }
    if (rw + 9 < 11) { int iw = (ow + 1 - rw) / 9 - 1; if (iw >= 0) { kwv[nw] = rw + 9; iwv[nw] = iw; nw++; } }
    float acc = b[oc];
    for (int a = 0; a < nh; ++a) {
        for (int bb = 0; bb < nw; ++bb) {
            const float* xp = x + (n * 64 * 50 + ihv[a]) * 60 + iwv[bb];
            const float* wp = w + (oc * 10 + khv[a]) * 11 + kwv[bb];
            #pragma unroll 4
            for (int c = 0; c < 64; ++c)
                acc += xp[c * 3000] * wp[c * 220];
        }
    }
    y[idx] = acc;
}

// finalize: perplexity from counts, loss from loss_sum
__global__ __launch_bounds__(512) void fin_k(const float* __restrict__ counts,
                                             const float* __restrict__ loss_sum,
                                             float* __restrict__ out, int out_size)
{
    __shared__ float red[512];
    int t = threadIdx.x;
    float c = counts[t];
    float p = c * (1.0f / 960.0f);
    red[t] = p * logf(p + 1e-10f);
    __syncthreads();
    for (int s = 256; s > 0; s >>= 1) {
        if (t < s) red[t] += red[t + s];
        __syncthreads();
    }
    if (t == 0) {
        out[out_size - 1] = expf(-red[0]);
        out[0] = loss_sum[0] * 1.25f / 61440.0f;
    }
}

extern "C" void kernel_launch(void* const* d_in, const int* in_sizes, int n_in,
                              void* d_out, int out_size, void* d_ws, size_t ws_size,
                              hipStream_t stream)
{
    const float* x          = (const float*)d_in[0];
    const float* enc_w1     = (const float*)d_in[1];
    const float* enc_b1     = (const float*)d_in[2];
    const float* enc_w2     = (const float*)d_in[3];
    const float* enc_b2     = (const float*)d_in[4];
    const float* enc_w3     = (const float*)d_in[5];
    const float* enc_b3     = (const float*)d_in[6];
    const float* enc_res_w1 = (const float*)d_in[7];
    const float* enc_res_w2 = (const float*)d_in[8];
    const float* pre_w      = (const float*)d_in[9];
    const float* pre_b      = (const float*)d_in[10];
    const float* emb        = (const float*)d_in[11];
    const float* dec_w1     = (const float*)d_in[12];
    const float* dec_b1     = (const float*)d_in[13];
    const float* dec_res_w1 = (const float*)d_in[14];
    const float* dec_res_w2 = (const float*)d_in[15];
    const float* dec_tw1    = (const float*)d_in[16];
    const float* dec_tb1    = (const float*)d_in[17];
    const float* dec_tw2    = (const float*)d_in[18];
    const float* dec_tb2    = (const float*)d_in[19];

    float* ws  = (float*)d_ws;
    float* out = (float*)d_out;

    float* h1       = ws;            // 6,758,400  (32,64,50,66)
    float* h2       = ws + 6758400;  // 122,880    (32,128,5,6)
    float* hA       = ws + 6881280;  // 122,880    (32,128,5,6)
    float* t64      = ws + 7004160;  // 61,440     (32,64,5,6)
    float* z        = ws + 7065600;  // 61,440     (32,64,5,6)
    float* qn       = ws + 7127040;  // 61,440     (32,64,5,6)
    float* counts   = ws + 7188480;  // 512
    float* loss_sum = ws + 7188992;  // 1
    float* dmid     = ws;            // reuse h1 region: 6,144,000 (32,64,50,60)

    hipMemsetAsync(counts, 0, 513 * sizeof(float), stream);

    // --- encoder ---
    conv1_k<<<1600, 256, 0, stream>>>(x, enc_w1, enc_b1, h1);
    conv2_k<<<160, 192, 0, stream>>>(h1, enc_w2, enc_b2, h2);
    conv3x3_k<<<480, 256, 0, stream>>>(h2, enc_w3, enc_b3, hA, 128, 128, 0);
    for (int i = 0; i < 2; ++i) {
        conv3x3_k<<<240, 256, 0, stream>>>(hA, enc_res_w1 + i * 73728, nullptr, t64, 128, 64, 1);
        res2_k<<<480, 256, 0, stream>>>(hA, t64, enc_res_w2 + i * 8192);
    }
    conv1x1_k<<<240, 256, 0, stream>>>(hA, pre_w, pre_b, z);

    // --- VQ ---
    vq_k<<<960, 64, 0, stream>>>(z, emb, qn, counts, loss_sum);

    // --- decoder ---
    conv3x3_k<<<480, 256, 0, stream>>>(qn, dec_w1, dec_b1, h2, 64, 128, 0);
    for (int i = 0; i < 2; ++i) {
        conv3x3_k<<<240, 256, 0, stream>>>(h2, dec_res_w1 + i * 73728, nullptr, t64, 128, 64, 1);
        res2_k<<<480, 256, 0, stream>>>(h2, t64, dec_res_w2 + i * 8192);
    }
    convt1_k<<<24000, 256, 0, stream>>>(h2, dec_tw1, dec_tb1, dmid);
    convt2_k<<<54000, 256, 0, stream>>>(dmid, dec_tw2, dec_tb2, out + 1);

    fin_k<<<1, 512, 0, stream>>>(counts, loss_sum, out, out_size);
}

// Round 3
// 1858.128 us; speedup vs baseline: 1.4908x; 1.4908x over previous
//
#include <hip/hip_runtime.h>
#include <math.h>

// ---------------------------------------------------------------------------
// VQ-VAE forward. Round 2 (resubmit): phase-decomposed transposed convs with
// padded inputs + repacked weights; conv2 rebuilt lane=oc with coalesced
// weights.
// ---------------------------------------------------------------------------

// conv1: x(32,2,400,600) w(64,2,10,11) s(8,9) p(1,1) -> y(32,64,50,66), +b, relu
__global__ __launch_bounds__(256) void conv1_k(const float* __restrict__ x,
                                               const float* __restrict__ w,
                                               const float* __restrict__ b,
                                               float* __restrict__ y)
{
    __shared__ float xs[2 * 10 * 596]; // 47.68 KB
    const int blk = blockIdx.x;            // 32*50 = 1600
    const int n = blk / 50, oh = blk % 50;
    const int tid = threadIdx.x;
    const int ih0 = oh * 8 - 1;
    for (int i = tid; i < 2 * 10 * 596; i += 256) {
        int c = i / 5960, rem = i % 5960;
        int r = rem / 596, j = rem % 596;
        int ih = ih0 + r, iw = j - 1;
        float v = 0.f;
        if (ih >= 0 && ih < 400 && iw >= 0 && iw < 600)
            v = x[((n * 2 + c) * 400 + ih) * 600 + iw];
        xs[i] = v;
    }
    __syncthreads();
    for (int i = tid; i < 32 * 66; i += 256) {
        int oc = i / 66, ow = i % 66;
        int col = ow * 9;
        float a0 = 0.f, a1 = 0.f;
        for (int c = 0; c < 2; ++c) {
            const float* wp0 = w + ((oc)      * 2 + c) * 110;
            const float* wp1 = w + ((oc + 32) * 2 + c) * 110;
            const float* xp  = xs + c * 5960 + col;
            for (int kh = 0; kh < 10; ++kh) {
                #pragma unroll
                for (int kw = 0; kw < 11; ++kw) {
                    float xv = xp[kh * 596 + kw];
                    a0 += xv * wp0[kh * 11 + kw];
                    a1 += xv * wp1[kh * 11 + kw];
                }
            }
        }
        y[((n * 64 + oc)      * 50 + oh) * 66 + ow] = fmaxf(a0 + b[oc], 0.f);
        y[((n * 64 + oc + 32) * 50 + oh) * 66 + ow] = fmaxf(a1 + b[oc + 32], 0.f);
    }
}

// repack OIHW -> [c][kh][kw][oc]
__global__ __launch_bounds__(256) void repack_oihw_k(const float* __restrict__ w,
                                                     float* __restrict__ wt,
                                                     int OC, int IC, int KH, int KW)
{
    int i = blockIdx.x * 256 + threadIdx.x;
    int total = OC * IC * KH * KW;
    if (i >= total) return;
    int oc = i % OC; int t = i / OC;
    int kw = t % KW; int kh = (t / KW) % KH; int c = t / (KW * KH);
    wt[i] = w[((oc * IC + c) * KH + kh) * KW + kw];
}

// repack IOHW (transposed-conv weights) -> [c][kh][kw][oc]
__global__ __launch_bounds__(256) void repack_iohw_k(const float* __restrict__ w,
                                                     float* __restrict__ wt,
                                                     int IC, int OC, int KH, int KW)
{
    int i = blockIdx.x * 256 + threadIdx.x;
    int total = OC * IC * KH * KW;
    if (i >= total) return;
    int oc = i % OC; int t = i / OC;
    int kw = t % KW; int kh = (t / KW) % KH; int c = t / (KW * KH);
    wt[i] = w[((c * OC + oc) * KH + kh) * KW + kw];
}

// conv2: h1(32,64,50,66) wt[c64][kh12][kw12][oc128] s10 p1 -> y(32,128,5,6), +b, relu
__global__ __launch_bounds__(512) void conv2_k2(const float* __restrict__ x,
                                                const float* __restrict__ wt,
                                                const float* __restrict__ b,
                                                float* __restrict__ y)
{
    __shared__ float xs[16 * 12 * 64];   // 49.2 KB
    __shared__ float sred[4 * 128 * 6];  // 12.3 KB
    const int tid = threadIdx.x;
    const int oc = tid & 127, sub = tid >> 7;  // sub = kh triplet
    const int n = blockIdx.x / 5, oh = blockIdx.x % 5;
    const int ih0 = oh * 10 - 1;
    float acc[6] = {0, 0, 0, 0, 0, 0};
    for (int cc = 0; cc < 4; ++cc) {
        __syncthreads();
        for (int i = tid; i < 12288; i += 512) {
            int col = i & 63; int t2 = i >> 6;
            int r = t2 % 12; int c = t2 / 12;
            int ih = ih0 + r, iw = col - 1;
            float v = 0.f;
            if (ih >= 0 && ih < 50 && iw >= 0 && iw < 66)
                v = x[((n * 64 + cc * 16 + c) * 50 + ih) * 66 + iw];
            xs[i] = v;
        }
        __syncthreads();
        for (int c = 0; c < 16; ++c) {
            for (int kh = sub * 3; kh < sub * 3 + 3; ++kh) {
                float xr[64];
                #pragma unroll
                for (int k = 0; k < 16; ++k)
                    *(float4*)&xr[4 * k] = *(const float4*)&xs[(c * 12 + kh) * 64 + 4 * k];
                const float* wp = wt + ((cc * 16 + c) * 144 + kh * 12) * 128 + oc;
                #pragma unroll
                for (int kw = 0; kw < 12; ++kw) {
                    float wv = wp[kw * 128];
                    #pragma unroll
                    for (int ow = 0; ow < 6; ++ow)
                        acc[ow] += xr[ow * 10 + kw] * wv;
                }
            }
        }
    }
    for (int j = 0; j < 6; ++j) sred[(sub * 128 + oc) * 6 + j] = acc[j];
    __syncthreads();
    if (sub == 0) {
        float bias = b[oc];
        #pragma unroll
        for (int j = 0; j < 6; ++j) {
            float v = acc[j] + sred[(128 + oc) * 6 + j] + sred[(256 + oc) * 6 + j]
                    + sred[(384 + oc) * 6 + j] + bias;
            y[((n * 128 + oc) * 5 + oh) * 6 + j] = fmaxf(v, 0.f);
        }
    }
}

// generic 3x3 conv on 5x6 spatial, pad 1, optional bias, optional relu on input
__global__ void conv3x3_k(const float* __restrict__ x, const float* __restrict__ w,
                          const float* __restrict__ b, float* __restrict__ y,
                          int Cin, int Cout, int relu_in)
{
    int idx = blockIdx.x * 256 + threadIdx.x;
    int total = 32 * Cout * 30;
    if (idx >= total) return;
    int ow = idx % 6, t = idx / 6;
    int oh = t % 5; t /= 5;
    int oc = t % Cout;
    int n = t / Cout;
    float acc = b ? b[oc] : 0.f;
    for (int kh = 0; kh < 3; ++kh) {
        int ih = oh - 1 + kh;
        if (ih < 0 || ih >= 5) continue;
        for (int kw = 0; kw < 3; ++kw) {
            int iw = ow - 1 + kw;
            if (iw < 0 || iw >= 6) continue;
            const float* xp = x + (n * Cin * 5 + ih) * 6 + iw;
            const float* wp = w + (oc * Cin * 3 + kh) * 3 + kw;
            #pragma unroll 4
            for (int c = 0; c < Cin; ++c) {
                float xv = xp[c * 30];
                if (relu_in) xv = fmaxf(xv, 0.f);
                acc += xv * wp[c * 9];
            }
        }
    }
    y[idx] = acc;
}

// residual 1x1: x(32,128,5,6) += sum_c w[o][c] * relu(t(32,64,5,6))
__global__ void res2_k(float* __restrict__ x, const float* __restrict__ t,
                       const float* __restrict__ w)
{
    int idx = blockIdx.x * 256 + threadIdx.x;
    if (idx >= 32 * 128 * 30) return;
    int ow = idx % 6;
    int oh = (idx / 6) % 5;
    int oc = (idx / 30) % 128;
    int n = idx / 3840;
    const float* tp = t + (n * 64 * 5 + oh) * 6 + ow;
    const float* wp = w + oc * 64;
    float acc = 0.f;
    #pragma unroll 4
    for (int c = 0; c < 64; ++c) acc += fmaxf(tp[c * 30], 0.f) * wp[c];
    x[idx] += acc;
}

// pre: z = conv1x1(relu(h)) 128->64 +b
__global__ void conv1x1_k(const float* __restrict__ x, const float* __restrict__ w,
                          const float* __restrict__ b, float* __restrict__ y)
{
    int idx = blockIdx.x * 256 + threadIdx.x;
    if (idx >= 32 * 64 * 30) return;
    int ow = idx % 6;
    int oh = (idx / 6) % 5;
    int oc = (idx / 30) % 64;
    int n = idx / 1920;
    const float* xp = x + (n * 128 * 5 + oh) * 6 + ow;
    const float* wp = w + oc * 128;
    float acc = b[oc];
    #pragma unroll 4
    for (int c = 0; c < 128; ++c) acc += fmaxf(xp[c * 30], 0.f) * wp[c];
    y[idx] = acc;
}

// VQ
__global__ __launch_bounds__(64) void vq_k(const float* __restrict__ z,
                                           const float* __restrict__ emb,
                                           float* __restrict__ qn,
                                           float* __restrict__ counts,
                                           float* __restrict__ loss_sum)
{
    const int r = blockIdx.x;          // 0..959
    const int lane = threadIdx.x;      // 0..63
    const int n = r / 30, hw = r % 30;
    __shared__ float zs[64];
    zs[lane] = z[(n * 64 + lane) * 30 + hw];
    __syncthreads();
    float best = 1e30f;
    int bestk = 0;
    for (int j = 0; j < 8; ++j) {
        int k = lane + j * 64;
        const float* ep = emb + k * 64;
        float dist = 0.f;
        #pragma unroll 8
        for (int d = 0; d < 64; ++d) {
            float df = ep[d] - zs[d];
            dist += df * df;
        }
        if (dist < best) { best = dist; bestk = k; }
    }
    for (int off = 32; off > 0; off >>= 1) {
        float ob = __shfl_down(best, off);
        int ok = __shfl_down(bestk, off);
        if (ob < best || (ob == best && ok < bestk)) { best = ob; bestk = ok; }
    }
    bestk = __shfl(bestk, 0);
    float ev = emb[bestk * 64 + lane];
    qn[(n * 64 + lane) * 30 + hw] = ev;
    float df = ev - zs[lane];
    df *= df;
    for (int off = 32; off > 0; off >>= 1) df += __shfl_down(df, off);
    if (lane == 0) {
        atomicAdd(loss_sum, df);
        atomicAdd(&counts[bestk], 1.0f);
    }
}

// xpad[n][c][7][8] = zero-padded relu(h2dec), interior rows 1..5 cols 1..6
__global__ __launch_bounds__(256) void xpad_k(const float* __restrict__ h,
                                              float* __restrict__ xp)
{
    int i = blockIdx.x * 256 + threadIdx.x;
    if (i >= 32 * 128 * 7 * 8) return;
    int col = i & 7; int t = i >> 3;
    int row = t % 7; t /= 7;
    int c = t % 128; int n = t / 128;
    float v = 0.f;
    if (row >= 1 && row <= 5 && col >= 1 && col <= 6)
        v = fmaxf(h[((n * 128 + c) * 5 + row - 1) * 6 + col - 1], 0.f);
    xp[i] = v;
}

// convt1: xpad(32,128,7,8) wt[c128][kh12][kw12][oc64] s10 p1 -> dmid_pad[32][64][52][62]
// writes relu(conv_t + bias) into interior rows 1..50 cols 1..60
__global__ __launch_bounds__(256) void convt1_k2(const float* __restrict__ xp,
                                                 const float* __restrict__ wt,
                                                 const float* __restrict__ b,
                                                 float* __restrict__ y)
{
    int gtid = blockIdx.x * 256 + threadIdx.x;
    int item = gtid >> 6;              // 16000 = (n32, io5, rh10, rw10)
    int lane = threadIdx.x & 63;       // oc
    int rw = item % 10; int t = item / 10;
    int rh = t % 10; t /= 10;
    int io = t % 5; int n = t / 5;
    int oh = 10 * io + (rh == 0 ? 9 : rh - 1);
    int kh0, i0, kh1 = 0, i1 = 0, nh = 1;
    if (rh == 0)      { kh0 = 0;  i0 = io + 1; kh1 = 10; i1 = io;     nh = 2; }
    else if (rh == 1) { kh0 = 1;  i0 = io;     kh1 = 11; i1 = io - 1; nh = 2; }
    else              { kh0 = rh; i0 = io; }
    int m0 = (rw == 0) ? 1 : 0;
    int kwa = rw, kwb = rw + 10;
    int nw = (rw < 2) ? 2 : 1;
    float acc[6] = {0, 0, 0, 0, 0, 0};
    for (int th = 0; th < nh; ++th) {
        int kh = th ? kh1 : kh0;
        int irow = th ? i1 : i0;
        const float* xr  = xp + ((n * 128) * 7 + irow + 1) * 8 + m0;
        const float* wpa = wt + (kh * 12 + kwa) * 64 + lane;
        const float* wpb = wt + (kh * 12 + kwb) * 64 + lane;
        for (int c = 0; c < 128; ++c) {
            float z[7];
            #pragma unroll
            for (int k = 0; k < 7; ++k) z[k] = xr[k];
            float wa = *wpa;
            #pragma unroll
            for (int j = 0; j < 6; ++j) acc[j] += z[j + 1] * wa;   // kwa: iw=m
            if (nw == 2) {
                float wb = *wpb;
                #pragma unroll
                for (int j = 0; j < 6; ++j) acc[j] += z[j] * wb;   // kwb: iw=m-1
            }
            xr += 56; wpa += 9216; wpb += 9216;
        }
    }
    float bias = b[lane];
    int colb = 10 * m0 + rw;           // (ow_0)+1
    float* yp = y + ((n * 64 + lane) * 52 + (oh + 1)) * 62 + colb;
    #pragma unroll
    for (int j = 0; j < 6; ++j) yp[10 * j] = fmaxf(acc[j] + bias, 0.f);
}

// convt2: dmid_pad[32][64][52][62] wt2[c64][kh10][kw11][oc2] s(8,9) p1 -> out(32,2,400,540)+b
__global__ __launch_bounds__(256) void convt2_k2(const float* __restrict__ xd,
                                                 const float* __restrict__ wt2g,
                                                 const float* __restrict__ bb,
                                                 float* __restrict__ out)
{
    __shared__ __align__(16) float wl[14080]; // 56.3 KB
    for (int i = threadIdx.x; i < 14080; i += 256) wl[i] = wt2g[i];
    __syncthreads();
    const int tid0 = blockIdx.x * 256 + threadIdx.x;
    const float b0 = bb[0], b1 = bb[1];
    for (int s = 0; s < 5; ++s) {
        int item = tid0 + s * 230400;   // (n32, io50, rh8, rw9, g10)
        int g = item % 10; int t = item / 10;
        int rw = t % 9; t /= 9;
        int rh = t % 8; t /= 8;
        int io = t % 50; int n = t / 50;
        int oh = 8 * io + (rh == 0 ? 7 : rh - 1);
        int kh0, i0, kh1 = 0, i1 = 0, nh = 1;
        if (rh == 0)      { kh0 = 0;  i0 = io + 1; kh1 = 8; i1 = io;     nh = 2; }
        else if (rh == 1) { kh0 = 1;  i0 = io;     kh1 = 9; i1 = io - 1; nh = 2; }
        else              { kh0 = rh; i0 = io; }
        int m0 = ((rw == 0) ? 1 : 0) + g * 6;
        int kwa = rw, kwb = rw + 9;
        int nw = (rw < 2) ? 2 : 1;
        float a0[6] = {0, 0, 0, 0, 0, 0}, a1[6] = {0, 0, 0, 0, 0, 0};
        for (int th = 0; th < nh; ++th) {
            int kh = th ? kh1 : kh0;
            int irow = th ? i1 : i0;
            const float* xr  = xd + ((n * 64) * 52 + irow + 1) * 62 + m0;
            const float* wpa = wl + (kh * 11 + kwa) * 2;
            const float* wpb = wl + (kh * 11 + kwb) * 2;
            for (int c = 0; c < 64; ++c) {
                float z[7];
                #pragma unroll
                for (int k = 0; k < 7; ++k) z[k] = xr[k];
                float2 wa = *(const float2*)wpa;
                #pragma unroll
                for (int j = 0; j < 6; ++j) { a0[j] += z[j + 1] * wa.x; a1[j] += z[j + 1] * wa.y; }
                if (nw == 2) {
                    float2 wb = *(const float2*)wpb;
                    #pragma unroll
                    for (int j = 0; j < 6; ++j) { a0[j] += z[j] * wb.x; a1[j] += z[j] * wb.y; }
                }
                xr += 3224; wpa += 220; wpb += 220;
            }
        }
        int colb = 9 * m0 + rw - 1;
        float* yp0 = out + ((n * 2 + 0) * 400 + oh) * 540 + colb;
        float* yp1 = out + ((n * 2 + 1) * 400 + oh) * 540 + colb;
        #pragma unroll
        for (int j = 0; j < 6; ++j) { yp0[9 * j] = a0[j] + b0; yp1[9 * j] = a1[j] + b1; }
    }
}

// finalize
__global__ __launch_bounds__(512) void fin_k(const float* __restrict__ counts,
                                             const float* __restrict__ loss_sum,
                                             float* __restrict__ out, int out_size)
{
    __shared__ float red[512];
    int t = threadIdx.x;
    float c = counts[t];
    float p = c * (1.0f / 960.0f);
    red[t] = p * logf(p + 1e-10f);
    __syncthreads();
    for (int s = 256; s > 0; s >>= 1) {
        if (t < s) red[t] += red[t + s];
        __syncthreads();
    }
    if (t == 0) {
        out[out_size - 1] = expf(-red[0]);
        out[0] = loss_sum[0] * 1.25f / 61440.0f;
    }
}

extern "C" void kernel_launch(void* const* d_in, const int* in_sizes, int n_in,
                              void* d_out, int out_size, void* d_ws, size_t ws_size,
                              hipStream_t stream)
{
    const float* x          = (const float*)d_in[0];
    const float* enc_w1     = (const float*)d_in[1];
    const float* enc_b1     = (const float*)d_in[2];
    const float* enc_w2     = (const float*)d_in[3];
    const float* enc_b2     = (const float*)d_in[4];
    const float* enc_w3     = (const float*)d_in[5];
    const float* enc_b3     = (const float*)d_in[6];
    const float* enc_res_w1 = (const float*)d_in[7];
    const float* enc_res_w2 = (const float*)d_in[8];
    const float* pre_w      = (const float*)d_in[9];
    const float* pre_b      = (const float*)d_in[10];
    const float* emb        = (const float*)d_in[11];
    const float* dec_w1     = (const float*)d_in[12];
    const float* dec_b1     = (const float*)d_in[13];
    const float* dec_res_w1 = (const float*)d_in[14];
    const float* dec_res_w2 = (const float*)d_in[15];
    const float* dec_tw1    = (const float*)d_in[16];
    const float* dec_tb1    = (const float*)d_in[17];
    const float* dec_tw2    = (const float*)d_in[18];
    const float* dec_tb2    = (const float*)d_in[19];

    float* ws  = (float*)d_ws;
    float* out = (float*)d_out;

    float* h1       = ws;            // 6,758,400 (32,64,50,66); later dmid_pad (6,601,728)
    float* h2       = ws + 6758400;  // 122,880
    float* hA       = ws + 6881280;  // 122,880
    float* t64      = ws + 7004160;  // 61,440
    float* z        = ws + 7065600;  // 61,440
    float* qn       = ws + 7127040;  // 61,440
    float* counts   = ws + 7188480;  // 512
    float* loss_sum = ws + 7188992;  // 1 (+pad)
    float* wtA      = ws + 7189056;  // 1,179,648 (conv2 repack, then convt1 repack)
    float* wt2      = ws + 8368704;  // 14,080
    float* xpad     = ws + 8382784;  // 229,376
    float* dmid     = ws;            // alias h1 region

    hipMemsetAsync(counts, 0, 513 * sizeof(float), stream);

    // --- encoder ---
    repack_oihw_k<<<4608, 256, 0, stream>>>(enc_w2, wtA, 128, 64, 12, 12);
    conv1_k<<<1600, 256, 0, stream>>>(x, enc_w1, enc_b1, h1);
    conv2_k2<<<160, 512, 0, stream>>>(h1, wtA, enc_b2, h2);
    conv3x3_k<<<480, 256, 0, stream>>>(h2, enc_w3, enc_b3, hA, 128, 128, 0);
    for (int i = 0; i < 2; ++i) {
        conv3x3_k<<<240, 256, 0, stream>>>(hA, enc_res_w1 + i * 73728, nullptr, t64, 128, 64, 1);
        res2_k<<<480, 256, 0, stream>>>(hA, t64, enc_res_w2 + i * 8192);
    }
    conv1x1_k<<<240, 256, 0, stream>>>(hA, pre_w, pre_b, z);

    // decoder weight repacks (wtA free after conv2)
    repack_iohw_k<<<4608, 256, 0, stream>>>(dec_tw1, wtA, 128, 64, 12, 12);
    repack_iohw_k<<<55, 256, 0, stream>>>(dec_tw2, wt2, 64, 2, 10, 11);

    // --- VQ ---
    vq_k<<<960, 64, 0, stream>>>(z, emb, qn, counts, loss_sum);

    // --- decoder ---
    conv3x3_k<<<480, 256, 0, stream>>>(qn, dec_w1, dec_b1, h2, 64, 128, 0);
    for (int i = 0; i < 2; ++i) {
        conv3x3_k<<<240, 256, 0, stream>>>(h2, dec_res_w1 + i * 73728, nullptr, t64, 128, 64, 1);
        res2_k<<<480, 256, 0, stream>>>(h2, t64, dec_res_w2 + i * 8192);
    }
    xpad_k<<<896, 256, 0, stream>>>(h2, xpad);
    hipMemsetAsync(dmid, 0, (size_t)6601728 * sizeof(float), stream);
    convt1_k2<<<4000, 256, 0, stream>>>(xpad, wtA, dec_tb1, dmid);
    convt2_k2<<<900, 256, 0, stream>>>(dmid, wt2, dec_tb2, out + 1);

    fin_k<<<1, 512, 0, stream>>>(counts, loss_sum, out, out_size);
}